// Round 6
// baseline (231.326 us; speedup 1.0000x reference)
//
#include <hip/hip_runtime.h>
#include <hip/hip_bf16.h>
#include <stdint.h>

// ExactAttention: B=2 N=2048 H=16 D=128, fp32 in [b,n,h,d], out fp32 [b,h,n,d], NO 1/sqrt(d).
// Round 6: R5 structure + T15 att[2] double-pipeline (QK(t) overlaps softmax+PV(t-1)),
// T5 setprio around MFMA clusters, tree-reduced softmax, fused conv kernel.
//  conv_kv: K fp32->f16 elementwise; V fp32->f16 transposed [b,h,d,n]. One launch.
//  attn32: 4 waves x 32q (128q/block), KVBLK=64; K dbuf, V dbuf (staggered stage);
//          S^T=mfma(K,Q) swapped -> lane-local softmax; P packed in-register;
//          O^T=mfma(V^T,P^T). One barrier per tile.
// Fallback (ws too small): verified round-2 kernel.

constexpr int Bb = 2, Nn = 2048, Hh = 16, Dd = 128;
constexpr int ROWSTR = Hh * Dd;                          // 2048 floats between consecutive n
constexpr size_t TEN = (size_t)Bb * Nn * Hh * Dd;        // 8388608
constexpr size_t WS_NEED = 2 * TEN * 2;                  // Kf16 + Vt f16 = 33.5MB

typedef __attribute__((ext_vector_type(8))) _Float16 f16x8;
typedef __attribute__((ext_vector_type(2))) __fp16 fp16x2;
typedef __attribute__((ext_vector_type(4))) float f32x4;
typedef __attribute__((ext_vector_type(16))) float f32x16;

__device__ __forceinline__ unsigned short f2h(float f) {
  union { _Float16 h; unsigned short u; } v;
  v.h = (_Float16)f;
  return v.u;
}

__device__ __forceinline__ unsigned pk2(float a, float b) {
  union { fp16x2 h; unsigned u; } v;
  v.h = __builtin_amdgcn_cvt_pkrtz(a, b);
  return v.u;
}

__device__ __forceinline__ void gload_lds16(const void* g, void* l) {
  __builtin_amdgcn_global_load_lds(
      (const __attribute__((address_space(1))) unsigned int*)g,
      (__attribute__((address_space(3))) unsigned int*)l, 16, 0, 0);
}

__device__ __forceinline__ f32x16 zero16() {
  f32x16 z;
#pragma unroll
  for (int i = 0; i < 16; ++i) z[i] = 0.f;
  return z;
}

// ---------------- conv_kv: K elementwise + V transposed, one launch ----------------
// blocks 0..4095: K fp32->f16 (256 thr x 8 elems). blocks 4096..5119: V -> [b,h,d,n].
__global__ __launch_bounds__(256) void conv_kv(
    const float* __restrict__ K, const float* __restrict__ V,
    _Float16* __restrict__ Kf, _Float16* __restrict__ Vt) {
  const int bid = blockIdx.x;
  if (bid < 4096) {
    size_t id = (size_t)bid * 256 + threadIdx.x;
    size_t e = id * 8;
    float4 a = *(const float4*)(K + e);
    float4 b = *(const float4*)(K + e + 4);
    f16x8 t;
    t[0] = (_Float16)a.x; t[1] = (_Float16)a.y; t[2] = (_Float16)a.z; t[3] = (_Float16)a.w;
    t[4] = (_Float16)b.x; t[5] = (_Float16)b.y; t[6] = (_Float16)b.z; t[7] = (_Float16)b.w;
    *(f16x8*)(Kf + e) = t;
  } else {
    __shared__ alignas(16) short T[128 * 72];  // rows of 144B (64 n + 8 pad f16)
    const int tid = threadIdx.x;
    const int vb = bid - 4096;          // 0..1023
    const int bh = vb >> 5;             // 0..31
    const int n0 = (vb & 31) * 64;
    const int h = bh & 15, b = bh >> 4;
    const float* src = V + (((size_t)b * Nn + n0) * Hh + h) * Dd;
#pragma unroll
    for (int it = 0; it < 8; ++it) {
      int id = it * 256 + tid;
      int f = id & 31, n = id >> 5;
      float4 a = *(const float4*)(src + (size_t)n * ROWSTR + f * 4);
      T[(4 * f + 0) * 72 + n] = (short)f2h(a.x);
      T[(4 * f + 1) * 72 + n] = (short)f2h(a.y);
      T[(4 * f + 2) * 72 + n] = (short)f2h(a.z);
      T[(4 * f + 3) * 72 + n] = (short)f2h(a.w);
    }
    __syncthreads();
    _Float16* dst = Vt + (size_t)bh * Dd * Nn + n0;
#pragma unroll
    for (int it = 0; it < 4; ++it) {
      int cid = it * 256 + tid;
      int d = cid >> 3, nc = cid & 7;
      f16x8 v = *(const f16x8*)((const char*)T + d * 144 + nc * 16);
      *(f16x8*)(dst + (size_t)d * Nn + nc * 8) = v;
    }
  }
}

// ---------------- attn32: pipelined 32x32x16 swapped-QK flash attention ----------------
// grid 512 (16 qb x 32 bh), 256 thr (4 waves x 32 q-rows). LDS 64KB:
// K dbuf @0/@16384 ([64kv][256B] swz ^((kv&15)<<4)), Vt dbuf @32768/@49152
// ([128d][128B] swz ^((d&7)<<4)). Schedule per iter kt:
//   STAGE K(kt+1), STAGE V(kt);  QK(kt)->cur;  softmax+pack+PV(kt-1) from prev;  barrier.
__global__ __launch_bounds__(256, 2) void attn32(
    const float* __restrict__ Q, const _Float16* __restrict__ Kf,
    const _Float16* __restrict__ Vt, float* __restrict__ O) {
  __shared__ alignas(16) char base[65536];

  const int tid = threadIdx.x;
  const int wave = tid >> 6;
  const int lane = tid & 63;
  const int l31 = lane & 31;
  const int hi = lane >> 5;

  // XCD swizzle: 512 = 8 XCD x 64; chunk per XCD = 4 heads x 16 q-blocks (KV L2-resident).
  const int raw = blockIdx.x;
  const int wg = (raw & 7) * 64 + (raw >> 3);
  const int qb = wg & 15;
  const int bh = wg >> 4;
  const int h = bh & 15, b = bh >> 4;

  const char* K0 = (const char*)Kf + ((size_t)b * Nn * Hh + h) * 256;   // n-row stride 4096B
  const char* V0 = (const char*)Vt + (size_t)bh * Dd * Nn * 2;          // d-row stride 4096B
  const float* Q0 = Q + ((size_t)b * Nn * Hh + h) * 128;                // fp32
  float* Ob = O + (size_t)bh * Nn * Dd;

  const int wq0 = qb * 128 + wave * 32;
  const int kswz = (l31 & 15) << 4;
  const int vswz = (l31 & 7) << 4;

#define STAGE_K(BUF, KT)                                                         \
  do {                                                                           \
    const char* ks_ = K0 + (size_t)(KT) * 64 * 4096;                             \
    char* kd_ = base + (BUF) * 16384;                                            \
    _Pragma("unroll") for (int i_ = 0; i_ < 4; ++i_) {                           \
      int ob_ = i_ * 4096 + wave * 1024;                                         \
      int o_ = ob_ + lane * 16;                                                  \
      int kv_ = o_ >> 8, ck_ = o_ & 255;                                         \
      gload_lds16(ks_ + (size_t)kv_ * 4096 + (ck_ ^ ((kv_ & 15) << 4)), kd_ + ob_); \
    }                                                                            \
  } while (0)

#define STAGE_V(BUF, KT)                                                         \
  do {                                                                           \
    const char* vs_ = V0 + (size_t)(KT) * 64 * 2;                                \
    char* vd_ = base + 32768 + (BUF) * 16384;                                    \
    _Pragma("unroll") for (int i_ = 0; i_ < 4; ++i_) {                           \
      int ob_ = i_ * 4096 + wave * 1024;                                         \
      int o_ = ob_ + lane * 16;                                                  \
      int d_ = o_ >> 7, cv_ = o_ & 127;                                          \
      gload_lds16(vs_ + (size_t)d_ * 4096 + (cv_ ^ ((d_ & 7) << 4)), vd_ + ob_); \
    }                                                                            \
  } while (0)

#define QK_TILE(BUF, S0, S1)                                                     \
  do {                                                                           \
    const char* KB_ = base + (BUF) * 16384;                                      \
    S0 = zero16();                                                               \
    S1 = zero16();                                                               \
    __builtin_amdgcn_s_setprio(1);                                               \
    _Pragma("unroll") for (int c_ = 0; c_ < 8; ++c_) {                           \
      const int colc_ = 32 * c_ + 16 * hi;                                       \
      f16x8 k0_ = *(const f16x8*)(KB_ + l31 * 256 + (colc_ ^ kswz));             \
      f16x8 k1_ = *(const f16x8*)(KB_ + (l31 + 32) * 256 + (colc_ ^ kswz));      \
      S0 = __builtin_amdgcn_mfma_f32_32x32x16_f16(k0_, qf[c_], S0, 0, 0, 0);     \
      S1 = __builtin_amdgcn_mfma_f32_32x32x16_f16(k1_, qf[c_], S1, 0, 0, 0);     \
    }                                                                            \
    __builtin_amdgcn_s_setprio(0);                                               \
  } while (0)

#define PACK1(SRC, KB_IDX, KSIDX)                                                \
  do {                                                                           \
    float v0_ = SRC[8 * (KB_IDX) + 0], v1_ = SRC[8 * (KB_IDX) + 1];              \
    float v2_ = SRC[8 * (KB_IDX) + 2], v3_ = SRC[8 * (KB_IDX) + 3];              \
    float v4_ = SRC[8 * (KB_IDX) + 4], v5_ = SRC[8 * (KB_IDX) + 5];              \
    float v6_ = SRC[8 * (KB_IDX) + 6], v7_ = SRC[8 * (KB_IDX) + 7];              \
    unsigned uA0_ = pk2(v0_, v1_), uA1_ = pk2(v2_, v3_);                         \
    unsigned uB0_ = pk2(v4_, v5_), uB1_ = pk2(v6_, v7_);                         \
    unsigned r0_ = (unsigned)__shfl_xor((int)(hi ? uA0_ : uB0_), 32);            \
    unsigned r1_ = (unsigned)__shfl_xor((int)(hi ? uA1_ : uB1_), 32);            \
    union { unsigned u[4]; f16x8 v; } t2_;                                       \
    t2_.u[0] = hi ? r0_ : uA0_;                                                  \
    t2_.u[1] = hi ? r1_ : uA1_;                                                  \
    t2_.u[2] = hi ? uB0_ : r0_;                                                  \
    t2_.u[3] = hi ? uB1_ : r1_;                                                  \
    pa_[KSIDX] = t2_.v;                                                          \
  } while (0)

// softmax + pack + PV for the tile held in (P0,P1); V buffer index VBUF.
#define SMAX_PV(P0, P1, VBUF)                                                    \
  do {                                                                           \
    const char* VB_ = base + 32768 + (VBUF) * 16384;                             \
    float t_[16];                                                                \
    _Pragma("unroll") for (int r_ = 0; r_ < 16; ++r_)                            \
        t_[r_] = fmaxf(P0[r_], P1[r_]);                                          \
    _Pragma("unroll") for (int w_ = 8; w_ >= 1; w_ >>= 1) {                      \
      _Pragma("unroll") for (int r_ = 0; r_ < w_; ++r_)                          \
          t_[r_] = fmaxf(t_[r_], t_[r_ + w_]);                                   \
    }                                                                            \
    float mx_ = fmaxf(t_[0], __shfl_xor(t_[0], 32));                             \
    if (!__all(mx_ <= m_run + 8.0f)) {                                           \
      float mn_ = fmaxf(m_run, mx_);                                             \
      float e_ = exp2f((m_run - mn_) * 1.44269504f);                             \
      l_run *= e_;                                                               \
      _Pragma("unroll") for (int dt_ = 0; dt_ < 4; ++dt_) {                      \
        _Pragma("unroll") for (int r_ = 0; r_ < 16; ++r_) acc[dt_][r_] *= e_;    \
      }                                                                          \
      m_run = mn_;                                                               \
    }                                                                            \
    float psA_[4] = {0.f, 0.f, 0.f, 0.f};                                        \
    _Pragma("unroll") for (int r_ = 0; r_ < 16; ++r_) {                          \
      float pv_ = exp2f((P0[r_] - m_run) * 1.44269504f);                         \
      P0[r_] = pv_;                                                              \
      psA_[r_ & 3] += pv_;                                                       \
    }                                                                            \
    _Pragma("unroll") for (int r_ = 0; r_ < 16; ++r_) {                          \
      float pv_ = exp2f((P1[r_] - m_run) * 1.44269504f);                         \
      P1[r_] = pv_;                                                              \
      psA_[r_ & 3] += pv_;                                                       \
    }                                                                            \
    float ps_ = (psA_[0] + psA_[1]) + (psA_[2] + psA_[3]);                       \
    ps_ += __shfl_xor(ps_, 32);                                                  \
    l_run += ps_;                                                                \
    f16x8 pa_[4];                                                                \
    PACK1(P0, 0, 0);                                                             \
    PACK1(P0, 1, 1);                                                             \
    PACK1(P1, 0, 2);                                                             \
    PACK1(P1, 1, 3);                                                             \
    __builtin_amdgcn_s_setprio(1);                                               \
    _Pragma("unroll") for (int dt_ = 0; dt_ < 4; ++dt_) {                        \
      const char* vrow_ = VB_ + (32 * dt_ + l31) * 128;                          \
      _Pragma("unroll") for (int ks_ = 0; ks_ < 4; ++ks_) {                      \
        f16x8 vf_ = *(const f16x8*)(vrow_ + ((32 * ks_ + 16 * hi) ^ vswz));      \
        acc[dt_] = __builtin_amdgcn_mfma_f32_32x32x16_f16(vf_, pa_[ks_],         \
                                                          acc[dt_], 0, 0, 0);   \
      }                                                                          \
    }                                                                            \
    __builtin_amdgcn_s_setprio(0);                                               \
  } while (0)

  // ---- prologue
  STAGE_K(0, 0);

  f16x8 qf[8];
  {
    const float* qp = Q0 + (size_t)(wq0 + l31) * ROWSTR;
#pragma unroll
    for (int c = 0; c < 8; ++c) {
      const float* p = qp + c * 16 + hi * 8;
      float4 a = *(const float4*)p;
      float4 bb = *(const float4*)(p + 4);
      f16x8 t;
      t[0] = (_Float16)a.x;  t[1] = (_Float16)a.y;
      t[2] = (_Float16)a.z;  t[3] = (_Float16)a.w;
      t[4] = (_Float16)bb.x; t[5] = (_Float16)bb.y;
      t[6] = (_Float16)bb.z; t[7] = (_Float16)bb.w;
      qf[c] = t;
    }
  }

  f32x16 acc[4];
#pragma unroll
  for (int dt = 0; dt < 4; ++dt) acc[dt] = zero16();
  float m_run = -INFINITY, l_run = 0.f;

  f32x16 sA0, sA1, sB0, sB1;

  __syncthreads();                 // K(0) ready
  STAGE_K(1, 1);
  STAGE_V(0, 0);
  QK_TILE(0, sA0, sA1);            // tile 0 -> sA
  __syncthreads();                 // K(1), V(0) ready

  for (int kt = 1; kt < 31; kt += 2) {
    // kt odd: cur = sB, prev = sA (tile kt-1), V-prev buf = (kt-1)&1 = 0
    STAGE_K((kt + 1) & 1, kt + 1);
    STAGE_V(kt & 1, kt);
    QK_TILE(kt & 1, sB0, sB1);
    SMAX_PV(sA0, sA1, 0);
    __syncthreads();
    // kt+1 even: cur = sA, prev = sB (tile kt), V-prev buf = kt&1 = 1
    STAGE_K((kt + 2) & 1, kt + 2);
    STAGE_V((kt + 1) & 1, kt + 1);
    QK_TILE((kt + 1) & 1, sA0, sA1);
    SMAX_PV(sB0, sB1, 1);
    __syncthreads();
  }
  // kt = 31 (odd): cur = sB; no further K stage.
  STAGE_V(1, 31);
  QK_TILE(1, sB0, sB1);
  SMAX_PV(sA0, sA1, 0);            // finish tile 30
  __syncthreads();                 // V(31) ready
  SMAX_PV(sB0, sB1, 1);            // finish tile 31

  // ---- epilogue: q = wq0+l31 lane-local
  const float invl = 1.0f / l_run;
  float* orow = Ob + (size_t)(wq0 + l31) * Dd;
#pragma unroll
  for (int dt = 0; dt < 4; ++dt)
#pragma unroll
    for (int r = 0; r < 16; ++r) {
      int d = 32 * dt + (r & 3) + 8 * (r >> 2) + 4 * hi;
      orow[d] = acc[dt][r] * invl;
    }

#undef STAGE_K
#undef STAGE_V
#undef QK_TILE
#undef PACK1
#undef SMAX_PV
}

// ---------------- Fallback: verified round-2 kernel (fp32 direct) ----------------
__global__ __launch_bounds__(256, 2) void attn_fwd_kernel(
    const float* __restrict__ Q, const float* __restrict__ K,
    const float* __restrict__ V, float* __restrict__ O) {
  __shared__ alignas(16) short Klds[64 * Dd];
  __shared__ alignas(16) short Vtlds[Dd * 64];
  __shared__ alignas(16) short Plds[4][16 * 64];

  const int tid = threadIdx.x;
  const int wave = tid >> 6;
  const int lane = tid & 63;
  const int g = lane >> 4;
  const int l15 = lane & 15;

  const int qb = blockIdx.x & 31;
  const int h = (blockIdx.x >> 5) & 15;
  const int b = blockIdx.x >> 9;

  const float* Qb = Q + ((size_t)b * Nn * Hh + h) * Dd;
  const float* Kb = K + ((size_t)b * Nn * Hh + h) * Dd;
  const float* Vb = V + ((size_t)b * Nn * Hh + h) * Dd;
  float* Ob = O + ((size_t)(b * Hh + h) * Nn) * Dd;

  const int qrow = qb * 64 + wave * 16 + l15;
  f16x8 qf[4];
  {
    const float* qp = Qb + (size_t)qrow * ROWSTR;
#pragma unroll
    for (int c = 0; c < 4; ++c) {
      const float* p = qp + c * 32 + g * 8;
      float4 a = *(const float4*)(p);
      float4 bb = *(const float4*)(p + 4);
      f16x8 t;
      t[0] = (_Float16)a.x;  t[1] = (_Float16)a.y;
      t[2] = (_Float16)a.z;  t[3] = (_Float16)a.w;
      t[4] = (_Float16)bb.x; t[5] = (_Float16)bb.y;
      t[6] = (_Float16)bb.z; t[7] = (_Float16)bb.w;
      qf[c] = t;
    }
  }

  f32x4 acc[8];
#pragma unroll
  for (int i = 0; i < 8; ++i) acc[i] = (f32x4){0.f, 0.f, 0.f, 0.f};
  float m_run[4], l_run[4];
#pragma unroll
  for (int r = 0; r < 4; ++r) { m_run[r] = -INFINITY; l_run[r] = 0.f; }

  char* KB = (char*)Klds;
  char* VB = (char*)Vtlds;
  char* PB = (char*)(Plds[wave]);

  for (int kt = 0; kt < Nn / 64; ++kt) {
    const int kv0 = kt * 64;
    __syncthreads();
#pragma unroll
    for (int i = 0; i < 8; ++i) {
      int id = i * 256 + tid;
      int f = id & 31;
      int kv = id >> 5;
      const float* p = Kb + (size_t)(kv0 + kv) * ROWSTR + f * 4;
      float4 a = *(const float4*)p;
      unsigned long long pk =
          (unsigned long long)f2h(a.x) | ((unsigned long long)f2h(a.y) << 16) |
          ((unsigned long long)f2h(a.z) << 32) | ((unsigned long long)f2h(a.w) << 48);
      int byte = kv * 256 + ((f * 8) ^ ((kv & 7) << 4));
      *(unsigned long long*)(KB + byte) = pk;
    }
#pragma unroll
    for (int i = 0; i < 8; ++i) {
      int id = i * 256 + tid;
      int d = id & 127;
      int kq = id >> 7;
      const float* p = Vb + (size_t)(kv0 + kq * 4) * ROWSTR + d;
      float v0 = p[0];
      float v1 = p[ROWSTR];
      float v2 = p[2 * ROWSTR];
      float v3 = p[3 * ROWSTR];
      unsigned long long pk =
          (unsigned long long)f2h(v0) | ((unsigned long long)f2h(v1) << 16) |
          ((unsigned long long)f2h(v2) << 32) | ((unsigned long long)f2h(v3) << 48);
      int byte = d * 128 + ((kq * 8) ^ ((d & 7) << 4));
      *(unsigned long long*)(VB + byte) = pk;
    }
    __syncthreads();

    f32x4 s[4];
#pragma unroll
    for (int t = 0; t < 4; ++t) {
      f32x4 cacc = (f32x4){0.f, 0.f, 0.f, 0.f};
      int row = t * 16 + l15;
#pragma unroll
      for (int c = 0; c < 4; ++c) {
        int byte = row * 256 + (((c * 64) + g * 16) ^ ((row & 7) << 4));
        f16x8 kf = *(const f16x8*)(KB + byte);
        cacc = __builtin_amdgcn_mfma_f32_16x16x32_f16(qf[c], kf, cacc, 0, 0, 0);
      }
      s[t] = cacc;
    }

#pragma unroll
    for (int r = 0; r < 4; ++r) {
      float mx = fmaxf(fmaxf(s[0][r], s[1][r]), fmaxf(s[2][r], s[3][r]));
      mx = fmaxf(mx, __shfl_xor(mx, 1));
      mx = fmaxf(mx, __shfl_xor(mx, 2));
      mx = fmaxf(mx, __shfl_xor(mx, 4));
      mx = fmaxf(mx, __shfl_xor(mx, 8));
      float mn = fmaxf(m_run[r], mx);
      float e = exp2f((m_run[r] - mn) * 1.44269504f);
      float ps = 0.f;
#pragma unroll
      for (int t = 0; t < 4; ++t) {
        float pv = exp2f((s[t][r] - mn) * 1.44269504f);
        s[t][r] = pv;
        ps += pv;
      }
      ps += __shfl_xor(ps, 1);
      ps += __shfl_xor(ps, 2);
      ps += __shfl_xor(ps, 4);
      ps += __shfl_xor(ps, 8);
      l_run[r] = l_run[r] * e + ps;
      m_run[r] = mn;
#pragma unroll
      for (int dt = 0; dt < 8; ++dt) acc[dt][r] *= e;
    }

#pragma unroll
    for (int t = 0; t < 4; ++t)
#pragma unroll
      for (int r = 0; r < 4; ++r) {
        int q = g * 4 + r;
        int kv = t * 16 + l15;
        int byte = q * 128 + ((kv * 2) ^ ((q & 7) << 4));
        *(unsigned short*)(PB + byte) = f2h(s[t][r]);
      }

#pragma unroll
    for (int c2 = 0; c2 < 2; ++c2) {
      int pbyte = l15 * 128 + (((c2 * 64) + g * 16) ^ ((l15 & 7) << 4));
      f16x8 pf = *(const f16x8*)(PB + pbyte);
#pragma unroll
      for (int dt = 0; dt < 8; ++dt) {
        int d = dt * 16 + l15;
        int vbyte = d * 128 + (((c2 * 64) + g * 16) ^ ((d & 7) << 4));
        f16x8 vf = *(const f16x8*)(VB + vbyte);
        acc[dt] = __builtin_amdgcn_mfma_f32_16x16x32_f16(pf, vf, acc[dt], 0, 0, 0);
      }
    }
  }

  const int qout = qb * 64 + wave * 16;
#pragma unroll
  for (int r = 0; r < 4; ++r) {
    float inv = 1.0f / l_run[r];
    float* op = Ob + (size_t)(qout + g * 4 + r) * Dd + l15;
#pragma unroll
    for (int dt = 0; dt < 8; ++dt) {
      op[dt * 16] = acc[dt][r] * inv;
    }
  }
}

extern "C" void kernel_launch(void* const* d_in, const int* in_sizes, int n_in,
                              void* d_out, int out_size, void* d_ws, size_t ws_size,
                              hipStream_t stream) {
  const float* Q = (const float*)d_in[0];
  const float* K = (const float*)d_in[1];
  const float* V = (const float*)d_in[2];
  float* O = (float*)d_out;

  if (ws_size >= WS_NEED) {
    _Float16* Kf = (_Float16*)d_ws;
    _Float16* Vt = Kf + TEN;
    conv_kv<<<dim3(5120), 256, 0, stream>>>(K, V, Kf, Vt);
    attn32<<<dim3(512), 256, 0, stream>>>(Q, Kf, Vt, O);
  } else {
    attn_fwd_kernel<<<dim3(1024), 256, 0, stream>>>(Q, K, V, O);
  }
}